// Round 7
// baseline (42.830 us; speedup 1.0000x reference)
//
#include <hip/hip_runtime.h>
#include <math.h>

// QNN forward — DIAGNOSTIC: full problem computed TWICE inside ONE dispatch
// (rep loop, pointers made opaque per-rep so the compiler can't CSE rep 2).
// Purpose: push dispatch duration above the harness's 39us poison-fills so
// rocprof's top-5 finally shows OUR kernel's FETCH/WRITE/VALUBusy/Occupancy.
// Output identical to single-pass (rep 2 overwrites with same values).
//
// cons layout (floats):
//   [0..31]  gates: qubit q at 8q: {g00r,g00i,g01r,g01i,g10r,g10i,g11r,g11i}
//   [32..79] wv[3][16] (CNOT-permuted Z/fc_w contraction weights)
//   [80..82] fc_b

#define QNN_BATCH 1048576

__device__ __forceinline__ int qnn_cnot_perm(int k, int c, int t) {
    int cbit = 1 << (3 - c), tbit = 1 << (3 - t);
    return (k & cbit) ? (k ^ tbit) : k;
}

#define QNN_CSTAGE(S, ga, gb)                                                   \
    do {                                                                        \
        const float g00r=(ga).x, g00i=(ga).y, g01r=(ga).z, g01i=(ga).w;         \
        const float g10r=(gb).x, g10i=(gb).y, g11r=(gb).z, g11i=(gb).w;         \
        _Pragma("unroll")                                                       \
        for (int base = 0; base < 16; base += 2 * (S)) {                        \
            _Pragma("unroll")                                                   \
            for (int k = 0; k < (S); ++k) {                                     \
                const int j0 = base + k, j1 = j0 + (S);                         \
                const float ar = yr[j0], ai = yi[j0];                           \
                const float br = yr[j1], bi = yi[j1];                           \
                yr[j0] = fmaf(g00r, ar, fmaf(-g00i, ai, fmaf(g01r, br, -g01i * bi))); \
                yi[j0] = fmaf(g00r, ai, fmaf( g00i, ar, fmaf(g01r, bi,  g01i * br))); \
                yr[j1] = fmaf(g10r, ar, fmaf(-g10i, ai, fmaf(g11r, br, -g11i * bi))); \
                yi[j1] = fmaf(g10r, ai, fmaf( g10i, ar, fmaf(g11r, bi,  g11i * br))); \
            }                                                                   \
        }                                                                       \
    } while (0)

__global__ __launch_bounds__(256) void qnn_fused(const float* __restrict__ x,
                                                 const float* __restrict__ params,
                                                 const float* __restrict__ fc_w,
                                                 const float* __restrict__ fc_b,
                                                 float* __restrict__ out) {
    __shared__ float cons[84];

    const int t = blockIdx.x * 256 + threadIdx.x;

    // Shared constants (once; not the object of study).
    if (threadIdx.x == 0) {
        for (int q = 0; q < 4; ++q) {
            float hx = 0.5f * params[q * 3 + 0];
            float hy = 0.5f * params[q * 3 + 1];
            float hz = 0.5f * params[q * 3 + 2];
            float cx = cosf(hx), sx = sinf(hx);
            float cy = cosf(hy), sy = sinf(hy);
            float cz = cosf(hz), sz = sinf(hz);
            float A = cy * cx, B = sy * sx, C = sy * cx, D = cy * sx;
            float* g = cons + q * 8;
            g[0] =  cz * A + sz * B;
            g[1] =  cz * B - sz * A;
            g[2] = -cz * C - sz * D;
            g[3] =  sz * C - cz * D;
            g[4] =  cz * C + sz * D;
            g[5] =  sz * C - cz * D;
            g[6] =  cz * A + sz * B;
            g[7] =  sz * A - cz * B;
        }
        for (int o = 0; o < 16; ++o) {
            int j = qnn_cnot_perm(qnn_cnot_perm(qnn_cnot_perm(o, 2, 3), 1, 2), 0, 1);
            for (int c = 0; c < 3; ++c) {
                float s = 0.f;
                for (int ww = 0; ww < 4; ++ww) {
                    float z = 1.f - 2.f * (float)((o >> (3 - ww)) & 1);
                    s += fc_w[c * 4 + ww] * z;
                }
                cons[32 + c * 16 + j] = s;
            }
        }
        for (int c = 0; c < 3; ++c) cons[80 + c] = fc_b[c];
    }
    __syncthreads();

    for (int rep = 0; rep < 2; ++rep) {
        // Opaque pointers: compiler cannot prove rep 2 reads/writes the same
        // addresses -> must re-load, re-compute, re-store (true 2x work).
        const float* xr = x;
        float* outr = out;
        asm volatile("" : "+s"(xr));
        asm volatile("" : "+s"(outr));

        const float4* xp = (const float4*)(xr + (size_t)t * 16);
        float4 v0 = xp[0], v1 = xp[1], v2 = xp[2], v3 = xp[3];

        float xv[16] = {v0.x, v0.y, v0.z, v0.w, v1.x, v1.y, v1.z, v1.w,
                        v2.x, v2.y, v2.z, v2.w, v3.x, v3.y, v3.z, v3.w};

        float n2;
        {
            float s0 = xv[0] * xv[0], s1 = xv[1] * xv[1];
            float s2 = xv[2] * xv[2], s3 = xv[3] * xv[3];
#pragma unroll
            for (int k = 1; k < 4; ++k) {
                s0 = fmaf(xv[4 * k + 0], xv[4 * k + 0], s0);
                s1 = fmaf(xv[4 * k + 1], xv[4 * k + 1], s1);
                s2 = fmaf(xv[4 * k + 2], xv[4 * k + 2], s2);
                s3 = fmaf(xv[4 * k + 3], xv[4 * k + 3], s3);
            }
            n2 = (s0 + s1) + (s2 + s3);
        }

        float yr[16], yi[16];
        {
            const float4 ga = *(const float4*)&cons[0];
            const float4 gb = *(const float4*)&cons[4];
#pragma unroll
            for (int k = 0; k < 8; ++k) {
                const float a = xv[k], b = xv[k + 8];
                yr[k]     = fmaf(ga.x, a, ga.z * b);
                yi[k]     = fmaf(ga.y, a, ga.w * b);
                yr[k + 8] = fmaf(gb.x, a, gb.z * b);
                yi[k + 8] = fmaf(gb.y, a, gb.w * b);
            }
        }
        {
            const float4 ga = *(const float4*)&cons[8],  gb = *(const float4*)&cons[12];
            QNN_CSTAGE(4, ga, gb);
        }
        {
            const float4 ga = *(const float4*)&cons[16], gb = *(const float4*)&cons[20];
            QNN_CSTAGE(2, ga, gb);
        }
        {
            const float4 ga = *(const float4*)&cons[24], gb = *(const float4*)&cons[28];
            QNN_CSTAGE(1, ga, gb);
        }

        float a0 = 0.f, a1 = 0.f, a2 = 0.f;
        float b0 = 0.f, b1 = 0.f, b2 = 0.f;
#pragma unroll
        for (int jb = 0; jb < 4; ++jb) {
            const int j = jb * 4;
            const float4 w0 = *(const float4*)&cons[32 + j];
            const float4 w1 = *(const float4*)&cons[48 + j];
            const float4 w2 = *(const float4*)&cons[64 + j];
            float p[4];
#pragma unroll
            for (int k = 0; k < 4; ++k)
                p[k] = fmaf(yr[j + k], yr[j + k], yi[j + k] * yi[j + k]);
            if ((jb & 1) == 0) {
                a0 = fmaf(w0.x, p[0], fmaf(w0.y, p[1], fmaf(w0.z, p[2], fmaf(w0.w, p[3], a0))));
                a1 = fmaf(w1.x, p[0], fmaf(w1.y, p[1], fmaf(w1.z, p[2], fmaf(w1.w, p[3], a1))));
                a2 = fmaf(w2.x, p[0], fmaf(w2.y, p[1], fmaf(w2.z, p[2], fmaf(w2.w, p[3], a2))));
            } else {
                b0 = fmaf(w0.x, p[0], fmaf(w0.y, p[1], fmaf(w0.z, p[2], fmaf(w0.w, p[3], b0))));
                b1 = fmaf(w1.x, p[0], fmaf(w1.y, p[1], fmaf(w1.z, p[2], fmaf(w1.w, p[3], b1))));
                b2 = fmaf(w2.x, p[0], fmaf(w2.y, p[1], fmaf(w2.z, p[2], fmaf(w2.w, p[3], b2))));
            }
        }

        const float inv = __builtin_amdgcn_rcpf(n2);
        float* o = outr + (size_t)t * 3;
        o[0] = fmaf(a0 + b0, inv, cons[80]);
        o[1] = fmaf(a1 + b1, inv, cons[81]);
        o[2] = fmaf(a2 + b2, inv, cons[82]);
    }
}

extern "C" void kernel_launch(void* const* d_in, const int* in_sizes, int n_in,
                              void* d_out, int out_size, void* d_ws, size_t ws_size,
                              hipStream_t stream) {
    (void)in_sizes; (void)n_in; (void)out_size; (void)d_ws; (void)ws_size;
    const float* x      = (const float*)d_in[0];
    const float* params = (const float*)d_in[1];
    const float* fc_w   = (const float*)d_in[2];
    const float* fc_b   = (const float*)d_in[3];
    float* out = (float*)d_out;

    qnn_fused<<<QNN_BATCH / 256, 256, 0, stream>>>(x, params, fc_w, fc_b, out);
}

// Round 8
// 26.337 us; speedup vs baseline: 1.6262x; 1.6262x over previous
//
#include <hip/hip_runtime.h>
#include <math.h>

// QNN forward, packed-FP32 (v_pk_fma_f32) version.
// State psi[16] packed as 8 x float2 (adjacent basis indices in one VGPR pair).
// Stages qubit0..2 (stride 8/4/2) are elementwise on the packed vectors;
// qubit3 (stride 1) uses lane-broadcasts (op_sel) + gates prepacked (g00,g10).
//
// cons layout (floats):
//   [0..15]   qubit0 gates, each duplicated {g,g}: order g00r,g00i,g01r,g01i,
//             g10r,g10i,g11r,g11i (pair i at [2i])
//   [16..31]  qubit1 gates duplicated
//   [32..47]  qubit2 gates duplicated
//   [48..55]  qubit3 packed pairs: {g00r,g10r},{g00i,g10i},{g01r,g11r},{g01i,g11i}
//   [56..103] wv[3][16] (CNOT-permuted Z/fc_w contraction weights)
//   [104..106] fc_b

#define QNN_BATCH 1048576

typedef float f2 __attribute__((ext_vector_type(2)));
typedef float vf4 __attribute__((ext_vector_type(4)));

#define FMA2(a, b, c) __builtin_elementwise_fma((a), (b), (c))

__device__ __forceinline__ int qnn_cnot_perm(int k, int c, int t) {
    int cbit = 1 << (3 - c), tbit = 1 << (3 - t);
    return (k & cbit) ? (k ^ tbit) : k;
}

// One packed complex butterfly: (a, b) <- gate x (a, b), all operands f2.
// g0=g00, g1=g01, g2=g10, g3=g11 as (re, im) f2 pairs (r=*_r, i=*_i).
__device__ __forceinline__ void qnn_cbf(f2& ar_, f2& ai_, f2& br_, f2& bi_,
                                        f2 g0r, f2 g0i, f2 g1r, f2 g1i,
                                        f2 g2r, f2 g2i, f2 g3r, f2 g3i) {
    const f2 ar = ar_, ai = ai_, br = br_, bi = bi_;
    ar_ = FMA2(g0r, ar, FMA2(-g0i, ai, FMA2(g1r, br, (-g1i) * bi)));
    ai_ = FMA2(g0r, ai, FMA2( g0i, ar, FMA2(g1r, bi,   g1i  * br)));
    br_ = FMA2(g2r, ar, FMA2(-g2i, ai, FMA2(g3r, br, (-g3i) * bi)));
    bi_ = FMA2(g2r, ai, FMA2( g2i, ar, FMA2(g3r, bi,   g3i  * br)));
}

__global__ __launch_bounds__(256) void qnn_fused(const float* __restrict__ x,
                                                 const float* __restrict__ params,
                                                 const float* __restrict__ fc_w,
                                                 const float* __restrict__ fc_b,
                                                 float* __restrict__ out) {
    __shared__ float cons[108];

    const int t = blockIdx.x * 256 + threadIdx.x;

    // Issue loads first (4 x dwordx4).
    const vf4* xp = (const vf4*)(x + (size_t)t * 16);
    vf4 V0 = xp[0], V1 = xp[1], V2 = xp[2], V3 = xp[3];

    // Thread 0 computes shared constants while loads are in flight.
    if (threadIdx.x == 0) {
        for (int q = 0; q < 4; ++q) {
            float hx = 0.5f * params[q * 3 + 0];
            float hy = 0.5f * params[q * 3 + 1];
            float hz = 0.5f * params[q * 3 + 2];
            float cx = cosf(hx), sx = sinf(hx);
            float cy = cosf(hy), sy = sinf(hy);
            float cz = cosf(hz), sz = sinf(hz);
            float A = cy * cx, B = sy * sx, C = sy * cx, D = cy * sx;
            float g[8];
            g[0] =  cz * A + sz * B;   // g00 re
            g[1] =  cz * B - sz * A;   // g00 im
            g[2] = -cz * C - sz * D;   // g01 re
            g[3] =  sz * C - cz * D;   // g01 im
            g[4] =  cz * C + sz * D;   // g10 re
            g[5] =  sz * C - cz * D;   // g10 im
            g[6] =  cz * A + sz * B;   // g11 re
            g[7] =  sz * A - cz * B;   // g11 im
            if (q < 3) {
                for (int i = 0; i < 8; ++i) {
                    cons[q * 16 + 2 * i]     = g[i];
                    cons[q * 16 + 2 * i + 1] = g[i];
                }
            } else {
                cons[48] = g[0]; cons[49] = g[4];  // (g00r, g10r)
                cons[50] = g[1]; cons[51] = g[5];  // (g00i, g10i)
                cons[52] = g[2]; cons[53] = g[6];  // (g01r, g11r)
                cons[54] = g[3]; cons[55] = g[7];  // (g01i, g11i)
            }
        }
        // wv[c][q(o)] = sum_w fc_w[c,w] * zsign(o,w);  q = p01 o p12 o p23
        for (int o = 0; o < 16; ++o) {
            int j = qnn_cnot_perm(qnn_cnot_perm(qnn_cnot_perm(o, 2, 3), 1, 2), 0, 1);
            for (int c = 0; c < 3; ++c) {
                float s = 0.f;
                for (int ww = 0; ww < 4; ++ww) {
                    float z = 1.f - 2.f * (float)((o >> (3 - ww)) & 1);
                    s += fc_w[c * 4 + ww] * z;
                }
                cons[56 + c * 16 + j] = s;
            }
        }
        for (int c = 0; c < 3; ++c) cons[104 + c] = fc_b[c];
    }
    __syncthreads();

    const f2* c2 = (const f2*)cons;

    // Packed state: X[m] = (x[2m], x[2m+1]).
    f2 X[8];
    X[0] = __builtin_shufflevector(V0, V0, 0, 1);
    X[1] = __builtin_shufflevector(V0, V0, 2, 3);
    X[2] = __builtin_shufflevector(V1, V1, 0, 1);
    X[3] = __builtin_shufflevector(V1, V1, 2, 3);
    X[4] = __builtin_shufflevector(V2, V2, 0, 1);
    X[5] = __builtin_shufflevector(V2, V2, 2, 3);
    X[6] = __builtin_shufflevector(V3, V3, 0, 1);
    X[7] = __builtin_shufflevector(V3, V3, 2, 3);

    // ||x||^2, packed then horizontal.
    f2 ns = X[0] * X[0];
#pragma unroll
    for (int m = 1; m < 8; ++m) ns = FMA2(X[m], X[m], ns);
    const float n2 = ns.x + ns.y;

    f2 YR[8], YI[8];
    // Qubit 0 (vector stride 4), real input.
    {
        f2 G[8];
#pragma unroll
        for (int i = 0; i < 8; ++i) G[i] = c2[i];
#pragma unroll
        for (int m = 0; m < 4; ++m) {
            const f2 a = X[m], b = X[m + 4];
            YR[m]     = FMA2(G[0], a, G[2] * b);
            YI[m]     = FMA2(G[1], a, G[3] * b);
            YR[m + 4] = FMA2(G[4], a, G[6] * b);
            YI[m + 4] = FMA2(G[5], a, G[7] * b);
        }
    }
    // Qubit 1 (vector stride 2): pairs m in {0,1,4,5}.
    {
        f2 G[8];
#pragma unroll
        for (int i = 0; i < 8; ++i) G[i] = c2[8 + i];
#pragma unroll
        for (int mm = 0; mm < 4; ++mm) {
            const int m = (mm & 1) + (mm >> 1) * 4;  // 0,1,4,5
            qnn_cbf(YR[m], YI[m], YR[m + 2], YI[m + 2],
                    G[0], G[1], G[2], G[3], G[4], G[5], G[6], G[7]);
        }
    }
    // Qubit 2 (vector stride 1): pairs m in {0,2,4,6}.
    {
        f2 G[8];
#pragma unroll
        for (int i = 0; i < 8; ++i) G[i] = c2[16 + i];
#pragma unroll
        for (int mm = 0; mm < 4; ++mm) {
            const int m = mm * 2;  // 0,2,4,6
            qnn_cbf(YR[m], YI[m], YR[m + 1], YI[m + 1],
                    G[0], G[1], G[2], G[3], G[4], G[5], G[6], G[7]);
        }
    }
    // Qubit 3 (intra-vector): lane-broadcasts + prepacked (g00,g10) gate pairs.
    {
        const f2 gA = c2[24], gB = c2[25], gC = c2[26], gD = c2[27];
#pragma unroll
        for (int m = 0; m < 8; ++m) {
            const f2 rl = __builtin_shufflevector(YR[m], YR[m], 0, 0);
            const f2 il = __builtin_shufflevector(YI[m], YI[m], 0, 0);
            const f2 rh = __builtin_shufflevector(YR[m], YR[m], 1, 1);
            const f2 ih = __builtin_shufflevector(YI[m], YI[m], 1, 1);
            YR[m] = FMA2(gA, rl, FMA2(-gB, il, FMA2(gC, rh, (-gD) * ih)));
            YI[m] = FMA2(gA, il, FMA2( gB, rl, FMA2(gC, ih,   gD  * rh)));
        }
    }

    // probs + 3-class contraction, packed (wv pairs are contiguous).
    f2 A0 = {0.f, 0.f}, A1 = {0.f, 0.f}, A2 = {0.f, 0.f};
#pragma unroll
    for (int m = 0; m < 8; ++m) {
        const f2 P = FMA2(YR[m], YR[m], YI[m] * YI[m]);
        A0 = FMA2(c2[28 + m], P, A0);
        A1 = FMA2(c2[36 + m], P, A1);
        A2 = FMA2(c2[44 + m], P, A2);
    }

    const float inv = __builtin_amdgcn_rcpf(n2);  // rel err ~1e-7 << 3.7e-2 threshold
    float* o = out + (size_t)t * 3;
    o[0] = fmaf(A0.x + A0.y, inv, cons[104]);
    o[1] = fmaf(A1.x + A1.y, inv, cons[105]);
    o[2] = fmaf(A2.x + A2.y, inv, cons[106]);
}

extern "C" void kernel_launch(void* const* d_in, const int* in_sizes, int n_in,
                              void* d_out, int out_size, void* d_ws, size_t ws_size,
                              hipStream_t stream) {
    (void)in_sizes; (void)n_in; (void)out_size; (void)d_ws; (void)ws_size;
    const float* x      = (const float*)d_in[0];
    const float* params = (const float*)d_in[1];
    const float* fc_w   = (const float*)d_in[2];
    const float* fc_b   = (const float*)d_in[3];
    float* out = (float*)d_out;

    qnn_fused<<<QNN_BATCH / 256, 256, 0, stream>>>(x, params, fc_w, fc_b, out);
}

// Round 9
// 23.651 us; speedup vs baseline: 1.8110x; 1.1136x over previous
//
#include <hip/hip_runtime.h>
#include <math.h>

// QNN forward, packed-FP32, grid-stride (2048 blocks x 2 tiles).
// logits[b,c] = fc_b[c] + (sum_j wv[c][j] |psi_j|^2) / n2,  n2 = sum_j |psi_j|^2
// (norm via unitarity: ||x||^2 == ||Ux||^2 — no separate norm pass).
//
// cons layout (floats):
//   [0..15]   qubit0 gates duplicated {g,g}: g00r,g00i,g01r,g01i,g10r,g10i,g11r,g11i
//   [16..31]  qubit1 gates duplicated
//   [32..47]  qubit2 gates duplicated
//   [48..55]  qubit3 packed pairs: {g00r,g10r},{g00i,g10i},{g01r,g11r},{g01i,g11i}
//   [56..103] wv[3][16] (CNOT-permuted Z/fc_w contraction weights)
//   [104..106] fc_b

#define QNN_BATCH 1048576

typedef float f2 __attribute__((ext_vector_type(2)));
typedef float vf4 __attribute__((ext_vector_type(4)));

#define FMA2(a, b, c) __builtin_elementwise_fma((a), (b), (c))

__device__ __forceinline__ int qnn_cnot_perm(int k, int c, int t) {
    int cbit = 1 << (3 - c), tbit = 1 << (3 - t);
    return (k & cbit) ? (k ^ tbit) : k;
}

// One packed complex butterfly: (a, b) <- gate x (a, b), all operands f2.
__device__ __forceinline__ void qnn_cbf(f2& ar_, f2& ai_, f2& br_, f2& bi_,
                                        f2 g0r, f2 g0i, f2 g1r, f2 g1i,
                                        f2 g2r, f2 g2i, f2 g3r, f2 g3i) {
    const f2 ar = ar_, ai = ai_, br = br_, bi = bi_;
    ar_ = FMA2(g0r, ar, FMA2(-g0i, ai, FMA2(g1r, br, (-g1i) * bi)));
    ai_ = FMA2(g0r, ai, FMA2( g0i, ar, FMA2(g1r, bi,   g1i  * br)));
    br_ = FMA2(g2r, ar, FMA2(-g2i, ai, FMA2(g3r, br, (-g3i) * bi)));
    bi_ = FMA2(g2r, ai, FMA2( g2i, ar, FMA2(g3r, bi,   g3i  * br)));
}

// Full per-sample pipeline from 4 loaded float4s; writes 3 floats to o.
__device__ __forceinline__ void qnn_sample(vf4 V0, vf4 V1, vf4 V2, vf4 V3,
                                           const f2* c2, const float* cons,
                                           float* o) {
    f2 X[8];
    X[0] = __builtin_shufflevector(V0, V0, 0, 1);
    X[1] = __builtin_shufflevector(V0, V0, 2, 3);
    X[2] = __builtin_shufflevector(V1, V1, 0, 1);
    X[3] = __builtin_shufflevector(V1, V1, 2, 3);
    X[4] = __builtin_shufflevector(V2, V2, 0, 1);
    X[5] = __builtin_shufflevector(V2, V2, 2, 3);
    X[6] = __builtin_shufflevector(V3, V3, 0, 1);
    X[7] = __builtin_shufflevector(V3, V3, 2, 3);

    f2 YR[8], YI[8];
    // Qubit 0 (vector stride 4), real input; X dies here.
    {
        f2 G[8];
#pragma unroll
        for (int i = 0; i < 8; ++i) G[i] = c2[i];
#pragma unroll
        for (int m = 0; m < 4; ++m) {
            const f2 a = X[m], b = X[m + 4];
            YR[m]     = FMA2(G[0], a, G[2] * b);
            YI[m]     = FMA2(G[1], a, G[3] * b);
            YR[m + 4] = FMA2(G[4], a, G[6] * b);
            YI[m + 4] = FMA2(G[5], a, G[7] * b);
        }
    }
    // Qubit 1 (vector stride 2): pairs m in {0,1,4,5}.
    {
        f2 G[8];
#pragma unroll
        for (int i = 0; i < 8; ++i) G[i] = c2[8 + i];
#pragma unroll
        for (int mm = 0; mm < 4; ++mm) {
            const int m = (mm & 1) + (mm >> 1) * 4;  // 0,1,4,5
            qnn_cbf(YR[m], YI[m], YR[m + 2], YI[m + 2],
                    G[0], G[1], G[2], G[3], G[4], G[5], G[6], G[7]);
        }
    }
    // Qubit 2 (vector stride 1): pairs m in {0,2,4,6}.
    {
        f2 G[8];
#pragma unroll
        for (int i = 0; i < 8; ++i) G[i] = c2[16 + i];
#pragma unroll
        for (int mm = 0; mm < 4; ++mm) {
            const int m = mm * 2;  // 0,2,4,6
            qnn_cbf(YR[m], YI[m], YR[m + 1], YI[m + 1],
                    G[0], G[1], G[2], G[3], G[4], G[5], G[6], G[7]);
        }
    }
    // Qubit 3 (intra-vector): lane-broadcasts + prepacked (g00,g10) pairs.
    {
        const f2 gA = c2[24], gB = c2[25], gC = c2[26], gD = c2[27];
#pragma unroll
        for (int m = 0; m < 8; ++m) {
            const f2 rl = __builtin_shufflevector(YR[m], YR[m], 0, 0);
            const f2 il = __builtin_shufflevector(YI[m], YI[m], 0, 0);
            const f2 rh = __builtin_shufflevector(YR[m], YR[m], 1, 1);
            const f2 ih = __builtin_shufflevector(YI[m], YI[m], 1, 1);
            YR[m] = FMA2(gA, rl, FMA2(-gB, il, FMA2(gC, rh, (-gD) * ih)));
            YI[m] = FMA2(gA, il, FMA2( gB, rl, FMA2(gC, ih,   gD  * rh)));
        }
    }

    // probs + 3-class contraction + n2 (= sum of probs, unitarity), packed.
    f2 A0 = {0.f, 0.f}, A1 = {0.f, 0.f}, A2 = {0.f, 0.f}, NS = {0.f, 0.f};
#pragma unroll
    for (int m = 0; m < 8; ++m) {
        const f2 P = FMA2(YR[m], YR[m], YI[m] * YI[m]);
        A0 = FMA2(c2[28 + m], P, A0);
        A1 = FMA2(c2[36 + m], P, A1);
        A2 = FMA2(c2[44 + m], P, A2);
        NS = NS + P;
    }

    const float inv = __builtin_amdgcn_rcpf(NS.x + NS.y);  // rel err ~1e-7
    o[0] = fmaf(A0.x + A0.y, inv, cons[104]);
    o[1] = fmaf(A1.x + A1.y, inv, cons[105]);
    o[2] = fmaf(A2.x + A2.y, inv, cons[106]);
}

__global__ __launch_bounds__(256) void qnn_fused(const float* __restrict__ x,
                                                 const float* __restrict__ params,
                                                 const float* __restrict__ fc_w,
                                                 const float* __restrict__ fc_b,
                                                 float* __restrict__ out) {
    __shared__ float cons[108];

    const size_t s0 = (size_t)blockIdx.x * 512 + threadIdx.x;  // tile0 sample
    // Issue tile-0 loads first.
    const vf4* xp0 = (const vf4*)(x + s0 * 16);
    vf4 A0v = xp0[0], A1v = xp0[1], A2v = xp0[2], A3v = xp0[3];

    // Thread 0 computes shared constants while tile-0 loads are in flight.
    if (threadIdx.x == 0) {
        for (int q = 0; q < 4; ++q) {
            float hx = 0.5f * params[q * 3 + 0];
            float hy = 0.5f * params[q * 3 + 1];
            float hz = 0.5f * params[q * 3 + 2];
            float cx = __cosf(hx), sx = __sinf(hx);
            float cy = __cosf(hy), sy = __sinf(hy);
            float cz = __cosf(hz), sz = __sinf(hz);
            float A = cy * cx, B = sy * sx, C = sy * cx, D = cy * sx;
            float g[8];
            g[0] =  cz * A + sz * B;   // g00 re
            g[1] =  cz * B - sz * A;   // g00 im
            g[2] = -cz * C - sz * D;   // g01 re
            g[3] =  sz * C - cz * D;   // g01 im
            g[4] =  cz * C + sz * D;   // g10 re
            g[5] =  sz * C - cz * D;   // g10 im
            g[6] =  cz * A + sz * B;   // g11 re
            g[7] =  sz * A - cz * B;   // g11 im
            if (q < 3) {
                for (int i = 0; i < 8; ++i) {
                    cons[q * 16 + 2 * i]     = g[i];
                    cons[q * 16 + 2 * i + 1] = g[i];
                }
            } else {
                cons[48] = g[0]; cons[49] = g[4];
                cons[50] = g[1]; cons[51] = g[5];
                cons[52] = g[2]; cons[53] = g[6];
                cons[54] = g[3]; cons[55] = g[7];
            }
        }
        // wv[c][q(o)] = sum_w fc_w[c,w] * zsign(o,w);  q = p01 o p12 o p23
        for (int o = 0; o < 16; ++o) {
            int j = qnn_cnot_perm(qnn_cnot_perm(qnn_cnot_perm(o, 2, 3), 1, 2), 0, 1);
            for (int c = 0; c < 3; ++c) {
                float s = 0.f;
                for (int ww = 0; ww < 4; ++ww) {
                    float z = 1.f - 2.f * (float)((o >> (3 - ww)) & 1);
                    s += fc_w[c * 4 + ww] * z;
                }
                cons[56 + c * 16 + j] = s;
            }
        }
        for (int c = 0; c < 3; ++c) cons[104 + c] = fc_b[c];
    }
    __syncthreads();

    // Prefetch tile-1 (hides L2/L3 latency under tile-0 compute).
    const vf4* xp1 = (const vf4*)(x + (s0 + 256) * 16);
    vf4 B0v = xp1[0], B1v = xp1[1], B2v = xp1[2], B3v = xp1[3];

    const f2* c2 = (const f2*)cons;
    qnn_sample(A0v, A1v, A2v, A3v, c2, cons, out + s0 * 3);
    qnn_sample(B0v, B1v, B2v, B3v, c2, cons, out + (s0 + 256) * 3);
}

extern "C" void kernel_launch(void* const* d_in, const int* in_sizes, int n_in,
                              void* d_out, int out_size, void* d_ws, size_t ws_size,
                              hipStream_t stream) {
    (void)in_sizes; (void)n_in; (void)out_size; (void)d_ws; (void)ws_size;
    const float* x      = (const float*)d_in[0];
    const float* params = (const float*)d_in[1];
    const float* fc_w   = (const float*)d_in[2];
    const float* fc_b   = (const float*)d_in[3];
    float* out = (float*)d_out;

    qnn_fused<<<QNN_BATCH / 512, 256, 0, stream>>>(x, params, fc_w, fc_b, out);
}

// Round 10
// 22.090 us; speedup vs baseline: 1.9389x; 1.0707x over previous
//
#include <hip/hip_runtime.h>
#include <math.h>

// QNN forward, packed-FP32, 1024 blocks x 4 tiles/thread, pipelined prefetch.
// logits[b,c] = fc_b[c] + (sum_j wv[c][j] |psi_j|^2) / n2,  n2 = sum_j |psi_j|^2
// (norm via unitarity: ||x||^2 == ||Ux||^2 — no separate norm pass).
//
// cons layout (floats):
//   [0..15]   qubit0 gates duplicated {g,g}: g00r,g00i,g01r,g01i,g10r,g10i,g11r,g11i
//   [16..31]  qubit1 gates duplicated
//   [32..47]  qubit2 gates duplicated
//   [48..55]  qubit3 packed pairs: {g00r,g10r},{g00i,g10i},{g01r,g11r},{g01i,g11i}
//   [56..103] wv[3][16] (CNOT-permuted Z/fc_w contraction weights)
//   [104..106] fc_b

#define QNN_BATCH 1048576
#define QNN_TILES 4

typedef float f2 __attribute__((ext_vector_type(2)));
typedef float vf4 __attribute__((ext_vector_type(4)));

#define FMA2(a, b, c) __builtin_elementwise_fma((a), (b), (c))

__device__ __forceinline__ int qnn_cnot_perm(int k, int c, int t) {
    int cbit = 1 << (3 - c), tbit = 1 << (3 - t);
    return (k & cbit) ? (k ^ tbit) : k;
}

// One packed complex butterfly: (a, b) <- gate x (a, b), all operands f2.
__device__ __forceinline__ void qnn_cbf(f2& ar_, f2& ai_, f2& br_, f2& bi_,
                                        f2 g0r, f2 g0i, f2 g1r, f2 g1i,
                                        f2 g2r, f2 g2i, f2 g3r, f2 g3i) {
    const f2 ar = ar_, ai = ai_, br = br_, bi = bi_;
    ar_ = FMA2(g0r, ar, FMA2(-g0i, ai, FMA2(g1r, br, (-g1i) * bi)));
    ai_ = FMA2(g0r, ai, FMA2( g0i, ar, FMA2(g1r, bi,   g1i  * br)));
    br_ = FMA2(g2r, ar, FMA2(-g2i, ai, FMA2(g3r, br, (-g3i) * bi)));
    bi_ = FMA2(g2r, ai, FMA2( g2i, ar, FMA2(g3r, bi,   g3i  * br)));
}

// Full per-sample pipeline from 4 loaded float4s; writes 3 floats to o.
__device__ __forceinline__ void qnn_sample(vf4 V0, vf4 V1, vf4 V2, vf4 V3,
                                           const f2* c2, const float* cons,
                                           float* o) {
    f2 X[8];
    X[0] = __builtin_shufflevector(V0, V0, 0, 1);
    X[1] = __builtin_shufflevector(V0, V0, 2, 3);
    X[2] = __builtin_shufflevector(V1, V1, 0, 1);
    X[3] = __builtin_shufflevector(V1, V1, 2, 3);
    X[4] = __builtin_shufflevector(V2, V2, 0, 1);
    X[5] = __builtin_shufflevector(V2, V2, 2, 3);
    X[6] = __builtin_shufflevector(V3, V3, 0, 1);
    X[7] = __builtin_shufflevector(V3, V3, 2, 3);

    f2 YR[8], YI[8];
    // Qubit 0 (vector stride 4), real input; X dies here.
    {
        f2 G[8];
#pragma unroll
        for (int i = 0; i < 8; ++i) G[i] = c2[i];
#pragma unroll
        for (int m = 0; m < 4; ++m) {
            const f2 a = X[m], b = X[m + 4];
            YR[m]     = FMA2(G[0], a, G[2] * b);
            YI[m]     = FMA2(G[1], a, G[3] * b);
            YR[m + 4] = FMA2(G[4], a, G[6] * b);
            YI[m + 4] = FMA2(G[5], a, G[7] * b);
        }
    }
    // Qubit 1 (vector stride 2): pairs m in {0,1,4,5}.
    {
        f2 G[8];
#pragma unroll
        for (int i = 0; i < 8; ++i) G[i] = c2[8 + i];
#pragma unroll
        for (int mm = 0; mm < 4; ++mm) {
            const int m = (mm & 1) + (mm >> 1) * 4;  // 0,1,4,5
            qnn_cbf(YR[m], YI[m], YR[m + 2], YI[m + 2],
                    G[0], G[1], G[2], G[3], G[4], G[5], G[6], G[7]);
        }
    }
    // Qubit 2 (vector stride 1): pairs m in {0,2,4,6}.
    {
        f2 G[8];
#pragma unroll
        for (int i = 0; i < 8; ++i) G[i] = c2[16 + i];
#pragma unroll
        for (int mm = 0; mm < 4; ++mm) {
            const int m = mm * 2;  // 0,2,4,6
            qnn_cbf(YR[m], YI[m], YR[m + 1], YI[m + 1],
                    G[0], G[1], G[2], G[3], G[4], G[5], G[6], G[7]);
        }
    }
    // Qubit 3 (intra-vector): lane-broadcasts + prepacked (g00,g10) pairs.
    {
        const f2 gA = c2[24], gB = c2[25], gC = c2[26], gD = c2[27];
#pragma unroll
        for (int m = 0; m < 8; ++m) {
            const f2 rl = __builtin_shufflevector(YR[m], YR[m], 0, 0);
            const f2 il = __builtin_shufflevector(YI[m], YI[m], 0, 0);
            const f2 rh = __builtin_shufflevector(YR[m], YR[m], 1, 1);
            const f2 ih = __builtin_shufflevector(YI[m], YI[m], 1, 1);
            YR[m] = FMA2(gA, rl, FMA2(-gB, il, FMA2(gC, rh, (-gD) * ih)));
            YI[m] = FMA2(gA, il, FMA2( gB, rl, FMA2(gC, ih,   gD  * rh)));
        }
    }

    // probs + 3-class contraction + n2 (= sum of probs, unitarity), packed.
    f2 A0 = {0.f, 0.f}, A1 = {0.f, 0.f}, A2 = {0.f, 0.f}, NS = {0.f, 0.f};
#pragma unroll
    for (int m = 0; m < 8; ++m) {
        const f2 P = FMA2(YR[m], YR[m], YI[m] * YI[m]);
        A0 = FMA2(c2[28 + m], P, A0);
        A1 = FMA2(c2[36 + m], P, A1);
        A2 = FMA2(c2[44 + m], P, A2);
        NS = NS + P;
    }

    const float inv = __builtin_amdgcn_rcpf(NS.x + NS.y);  // rel err ~1e-7
    o[0] = fmaf(A0.x + A0.y, inv, cons[104]);
    o[1] = fmaf(A1.x + A1.y, inv, cons[105]);
    o[2] = fmaf(A2.x + A2.y, inv, cons[106]);
}

__global__ __launch_bounds__(256) void qnn_fused(const float* __restrict__ x,
                                                 const float* __restrict__ params,
                                                 const float* __restrict__ fc_w,
                                                 const float* __restrict__ fc_b,
                                                 float* __restrict__ out) {
    __shared__ float cons[108];

    // Block handles QNN_TILES consecutive 256-sample tiles.
    const size_t s0 = (size_t)blockIdx.x * (256 * QNN_TILES) + threadIdx.x;

    // Issue tile-0 loads first.
    const vf4* xp = (const vf4*)(x + s0 * 16);
    vf4 cur0 = xp[0], cur1 = xp[1], cur2 = xp[2], cur3 = xp[3];

    // Thread 0 computes shared constants while tile-0 loads are in flight.
    if (threadIdx.x == 0) {
        for (int q = 0; q < 4; ++q) {
            float hx = 0.5f * params[q * 3 + 0];
            float hy = 0.5f * params[q * 3 + 1];
            float hz = 0.5f * params[q * 3 + 2];
            float cx = __cosf(hx), sx = __sinf(hx);
            float cy = __cosf(hy), sy = __sinf(hy);
            float cz = __cosf(hz), sz = __sinf(hz);
            float A = cy * cx, B = sy * sx, C = sy * cx, D = cy * sx;
            float g[8];
            g[0] =  cz * A + sz * B;   // g00 re
            g[1] =  cz * B - sz * A;   // g00 im
            g[2] = -cz * C - sz * D;   // g01 re
            g[3] =  sz * C - cz * D;   // g01 im
            g[4] =  cz * C + sz * D;   // g10 re
            g[5] =  sz * C - cz * D;   // g10 im
            g[6] =  cz * A + sz * B;   // g11 re
            g[7] =  sz * A - cz * B;   // g11 im
            if (q < 3) {
                for (int i = 0; i < 8; ++i) {
                    cons[q * 16 + 2 * i]     = g[i];
                    cons[q * 16 + 2 * i + 1] = g[i];
                }
            } else {
                cons[48] = g[0]; cons[49] = g[4];
                cons[50] = g[1]; cons[51] = g[5];
                cons[52] = g[2]; cons[53] = g[6];
                cons[54] = g[3]; cons[55] = g[7];
            }
        }
        // wv[c][q(o)] = sum_w fc_w[c,w] * zsign(o,w);  q = p01 o p12 o p23
        for (int o = 0; o < 16; ++o) {
            int j = qnn_cnot_perm(qnn_cnot_perm(qnn_cnot_perm(o, 2, 3), 1, 2), 0, 1);
            for (int c = 0; c < 3; ++c) {
                float s = 0.f;
                for (int ww = 0; ww < 4; ++ww) {
                    float z = 1.f - 2.f * (float)((o >> (3 - ww)) & 1);
                    s += fc_w[c * 4 + ww] * z;
                }
                cons[56 + c * 16 + j] = s;
            }
        }
        for (int c = 0; c < 3; ++c) cons[104 + c] = fc_b[c];
    }
    __syncthreads();

    const f2* c2 = (const f2*)cons;

    // Software pipeline: prefetch tile k+1 while computing tile k.
#pragma unroll
    for (int k = 0; k < QNN_TILES; ++k) {
        vf4 nxt0, nxt1, nxt2, nxt3;
        if (k + 1 < QNN_TILES) {
            const vf4* xn = (const vf4*)(x + (s0 + (size_t)(k + 1) * 256) * 16);
            nxt0 = xn[0]; nxt1 = xn[1]; nxt2 = xn[2]; nxt3 = xn[3];
        }
        qnn_sample(cur0, cur1, cur2, cur3, c2, cons,
                   out + (s0 + (size_t)k * 256) * 3);
        if (k + 1 < QNN_TILES) {
            cur0 = nxt0; cur1 = nxt1; cur2 = nxt2; cur3 = nxt3;
        }
    }
}

extern "C" void kernel_launch(void* const* d_in, const int* in_sizes, int n_in,
                              void* d_out, int out_size, void* d_ws, size_t ws_size,
                              hipStream_t stream) {
    (void)in_sizes; (void)n_in; (void)out_size; (void)d_ws; (void)ws_size;
    const float* x      = (const float*)d_in[0];
    const float* params = (const float*)d_in[1];
    const float* fc_w   = (const float*)d_in[2];
    const float* fc_b   = (const float*)d_in[3];
    float* out = (float*)d_out;

    qnn_fused<<<QNN_BATCH / (256 * QNN_TILES), 256, 0, stream>>>(x, params, fc_w, fc_b, out);
}

// Round 11
// 18.548 us; speedup vs baseline: 2.3091x; 1.1909x over previous
//
#include <hip/hip_runtime.h>
#include <math.h>

// QNN forward via MFMA:
//   psi_cat = M @ x  with M = [Re(U_kron); Im(U_kron)]  (32x16, bf16 A-frag)
//   one v_mfma_f32_32x32x16_bf16 per 32 samples; CNOT perm folded into wv;
//   norm via unitarity (n2 = sum_j |psi_j|^2).
// Wave-tile = 64 samples = 2 MFMAs. Block = 4 waves, QNN_TILES tiles/block.
//
// Fragment layouts (guide-verified for 32x32x16 bf16):
//   A[row][k]: lane = row + 32*(k>>3), elem i = k&7   (8 bf16/lane)
//   B[k][n]:   lane = n  + 32*(k>>3), elem i = k&7   -> 8 consecutive floats
//              of sample n: two dwordx4 + 4 cvt_pk
//   D[row][col]: col = lane&31, row = (reg&3)+8*(reg>>2)+4*(lane>>5)
//     => lane holds yr_j (reg i) and yi_j (reg i+8) for j = (i&3)+8*(i>>2)+4h

#define QNN_BATCH 1048576
#define QNN_TILES 4

typedef float f32x16 __attribute__((ext_vector_type(16)));
typedef short bf16x8 __attribute__((ext_vector_type(8)));
typedef unsigned u32x4 __attribute__((ext_vector_type(4)));
typedef float vf4 __attribute__((ext_vector_type(4)));

__device__ __forceinline__ unsigned qnn_cvtpk(float lo, float hi) {
    unsigned r;
    asm("v_cvt_pk_bf16_f32 %0, %1, %2" : "=v"(r) : "v"(lo), "v"(hi));
    return r;
}

__device__ __forceinline__ int qnn_cnot_perm(int k, int c, int t) {
    int cbit = 1 << (3 - c), tbit = 1 << (3 - t);
    return (k & cbit) ? (k ^ tbit) : k;
}

__device__ __forceinline__ bf16x8 qnn_bfrag(vf4 a, vf4 b) {
    u32x4 u;
    u.x = qnn_cvtpk(a.x, a.y);
    u.y = qnn_cvtpk(a.z, a.w);
    u.z = qnn_cvtpk(b.x, b.y);
    u.w = qnn_cvtpk(b.z, b.w);
    return __builtin_bit_cast(bf16x8, u);
}

__global__ __launch_bounds__(256) void qnn_mfma(const float* __restrict__ x,
                                                const float* __restrict__ params,
                                                const float* __restrict__ fc_w,
                                                const float* __restrict__ fc_b,
                                                float* __restrict__ out) {
    __shared__ float g4[4][8];                 // per-qubit gates
    __shared__ float u01r[16], u01i[16];       // U0 (x) U1  (4x4 complex)
    __shared__ float u23r[16], u23i[16];       // U2 (x) U3
    __shared__ unsigned short afrag_lds[512];  // M as bf16 A-fragment
    __shared__ float wv_lds[48];               // wv[3][16], CNOT-permuted
    __shared__ float bias_lds[3];

    const int tid  = threadIdx.x;
    const int lane = tid & 63;
    const int wv_w = tid >> 6;          // wave id 0..3
    const int h    = lane >> 5;         // lane half (k-half / j-half)
    const int col  = lane & 31;         // sample column within mfma

    // ---- Issue tile-0 loads first (hide setup under them). ----
    const size_t blk0 = (size_t)blockIdx.x * (256 * QNN_TILES);
    const size_t wb0  = blk0 + wv_w * 64;          // tile 0, this wave
    const float* pa0 = x + (wb0 + col) * 16 + h * 8;
    const float* pb0 = x + (wb0 + 32 + col) * 16 + h * 8;
    vf4 cA0 = *(const vf4*)pa0, cA1 = *(const vf4*)(pa0 + 4);
    vf4 cB0 = *(const vf4*)pb0, cB1 = *(const vf4*)(pb0 + 4);

    // ---- Setup phase 1: gates (threads 0-3, one qubit each). ----
    if (tid < 4) {
        const int q = tid;
        float hx = 0.5f * params[q * 3 + 0];
        float hy = 0.5f * params[q * 3 + 1];
        float hz = 0.5f * params[q * 3 + 2];
        float cx = __cosf(hx), sx = __sinf(hx);
        float cy = __cosf(hy), sy = __sinf(hy);
        float cz = __cosf(hz), sz = __sinf(hz);
        float A = cy * cx, B = sy * sx, C = sy * cx, D = cy * sx;
        g4[q][0] =  cz * A + sz * B;   // g00 re
        g4[q][1] =  cz * B - sz * A;   // g00 im
        g4[q][2] = -cz * C - sz * D;   // g01 re
        g4[q][3] =  sz * C - cz * D;   // g01 im
        g4[q][4] =  cz * C + sz * D;   // g10 re
        g4[q][5] =  sz * C - cz * D;   // g10 im
        g4[q][6] =  cz * A + sz * B;   // g11 re
        g4[q][7] =  sz * A - cz * B;   // g11 im
    }
    __syncthreads();

    // ---- Setup phase 2: 4x4 krons, wv, bias (parallel). ----
    if (tid < 32) {
        const int e = tid & 15, a = e >> 2, b = e & 3;
        const int q0 = (tid < 16) ? 0 : 2, q1 = q0 + 1;
        const float xr = g4[q0][4 * (a >> 1) + 2 * (b >> 1)];
        const float xi = g4[q0][4 * (a >> 1) + 2 * (b >> 1) + 1];
        const float yr = g4[q1][4 * (a & 1) + 2 * (b & 1)];
        const float yi = g4[q1][4 * (a & 1) + 2 * (b & 1) + 1];
        if (tid < 16) { u01r[e] = xr * yr - xi * yi; u01i[e] = xr * yi + xi * yr; }
        else          { u23r[e] = xr * yr - xi * yi; u23i[e] = xr * yi + xi * yr; }
    } else if (tid >= 64 && tid < 112) {
        const int idx = tid - 64, c = idx >> 4, o = idx & 15;
        const int j = qnn_cnot_perm(qnn_cnot_perm(qnn_cnot_perm(o, 2, 3), 1, 2), 0, 1);
        float s = 0.f;
        for (int ww = 0; ww < 4; ++ww) {
            float z = 1.f - 2.f * (float)((o >> (3 - ww)) & 1);
            s += fc_w[c * 4 + ww] * z;
        }
        wv_lds[c * 16 + j] = s;
    } else if (tid >= 112 && tid < 115) {
        bias_lds[tid - 112] = fc_b[tid - 112];
    }
    __syncthreads();

    // ---- Setup phase 3: M entry (j,k) per thread -> bf16 A-fragment. ----
    {
        const int j = tid >> 4, k = tid & 15;
        const float ar = u01r[(j >> 2) * 4 + (k >> 2)];
        const float ai = u01i[(j >> 2) * 4 + (k >> 2)];
        const float br = u23r[(j & 3) * 4 + (k & 3)];
        const float bi = u23i[(j & 3) * 4 + (k & 3)];
        const float re = ar * br - ai * bi;   // M[j][k]   (row j    = Re)
        const float im = ar * bi + ai * br;   // M[j+16][k] (row j+16 = Im)
        const unsigned pk = qnn_cvtpk(re, im);
        const int laneR = j + ((k >> 3) << 5);
        const int laneI = (j + 16) + ((k >> 3) << 5);
        afrag_lds[laneR * 8 + (k & 7)] = (unsigned short)(pk & 0xffffu);
        afrag_lds[laneI * 8 + (k & 7)] = (unsigned short)(pk >> 16);
    }
    __syncthreads();

    // ---- Per-lane persistent fragments. ----
    const bf16x8 afrag = *(const bf16x8*)&afrag_lds[lane * 8];
    float wv0[8], wv1[8], wv2[8];
#pragma unroll
    for (int i = 0; i < 8; ++i) {
        const int j = (i & 3) + 8 * (i >> 2) + 4 * h;
        wv0[i] = wv_lds[j];
        wv1[i] = wv_lds[16 + j];
        wv2[i] = wv_lds[32 + j];
    }
    const float bs0 = bias_lds[0], bs1 = bias_lds[1], bs2 = bias_lds[2];

    // ---- Tile loop with distance-1 prefetch. ----
#pragma unroll
    for (int k = 0; k < QNN_TILES; ++k) {
        vf4 nA0, nA1, nB0, nB1;
        if (k + 1 < QNN_TILES) {
            const size_t wbn = blk0 + (size_t)(k + 1) * 256 + wv_w * 64;
            const float* pa = x + (wbn + col) * 16 + h * 8;
            const float* pb = x + (wbn + 32 + col) * 16 + h * 8;
            nA0 = *(const vf4*)pa; nA1 = *(const vf4*)(pa + 4);
            nB0 = *(const vf4*)pb; nB1 = *(const vf4*)(pb + 4);
        }

        const bf16x8 fb0 = qnn_bfrag(cA0, cA1);
        const bf16x8 fb1 = qnn_bfrag(cB0, cB1);
        f32x16 zacc = {0.f,0.f,0.f,0.f,0.f,0.f,0.f,0.f,
                       0.f,0.f,0.f,0.f,0.f,0.f,0.f,0.f};
        const f32x16 d0 = __builtin_amdgcn_mfma_f32_32x32x16_bf16(afrag, fb0, zacc, 0, 0, 0);
        const f32x16 d1 = __builtin_amdgcn_mfma_f32_32x32x16_bf16(afrag, fb1, zacc, 0, 0, 0);

        // probs + partial contraction for each mfma (lane-local 8 j's).
        float pA[8], pB[8];
#pragma unroll
        for (int i = 0; i < 8; ++i) {
            pA[i] = fmaf(d0[i], d0[i], d0[i + 8] * d0[i + 8]);
            pB[i] = fmaf(d1[i], d1[i], d1[i + 8] * d1[i + 8]);
        }
        float LA0 = 0.f, LA1 = 0.f, LA2 = 0.f;
        float LB0 = 0.f, LB1 = 0.f, LB2 = 0.f;
#pragma unroll
        for (int i = 0; i < 8; ++i) {
            LA0 = fmaf(wv0[i], pA[i], LA0);
            LA1 = fmaf(wv1[i], pA[i], LA1);
            LA2 = fmaf(wv2[i], pA[i], LA2);
            LB0 = fmaf(wv0[i], pB[i], LB0);
            LB1 = fmaf(wv1[i], pB[i], LB1);
            LB2 = fmaf(wv2[i], pB[i], LB2);
        }
        const float NSA = ((pA[0] + pA[1]) + (pA[2] + pA[3])) +
                          ((pA[4] + pA[5]) + (pA[6] + pA[7]));
        const float NSB = ((pB[0] + pB[1]) + (pB[2] + pB[3])) +
                          ((pB[4] + pB[5]) + (pB[6] + pB[7]));

        // Exchange: lane keeps mfma_h (h=0 -> mfma0); sends the other's
        // partials to its pair lane (l ^ 32), which is the lane that keeps it.
        const float s0 = h ? LA0 : LB0, s1 = h ? LA1 : LB1;
        const float s2 = h ? LA2 : LB2, s3 = h ? NSA : NSB;
        const float r0 = __shfl_xor(s0, 32, 64);
        const float r1 = __shfl_xor(s1, 32, 64);
        const float r2 = __shfl_xor(s2, 32, 64);
        const float r3 = __shfl_xor(s3, 32, 64);
        const float L0 = (h ? LB0 : LA0) + r0;
        const float L1 = (h ? LB1 : LA1) + r1;
        const float L2 = (h ? LB2 : LA2) + r2;
        const float NS = (h ? NSB : NSA) + r3;

        const float inv = __builtin_amdgcn_rcpf(NS);
        const size_t wb = blk0 + (size_t)k * 256 + wv_w * 64;
        float* o = out + (wb + lane) * 3;
        o[0] = fmaf(L0, inv, bs0);
        o[1] = fmaf(L1, inv, bs1);
        o[2] = fmaf(L2, inv, bs2);

        if (k + 1 < QNN_TILES) { cA0 = nA0; cA1 = nA1; cB0 = nB0; cB1 = nB1; }
    }
}

extern "C" void kernel_launch(void* const* d_in, const int* in_sizes, int n_in,
                              void* d_out, int out_size, void* d_ws, size_t ws_size,
                              hipStream_t stream) {
    (void)in_sizes; (void)n_in; (void)out_size; (void)d_ws; (void)ws_size;
    const float* x      = (const float*)d_in[0];
    const float* params = (const float*)d_in[1];
    const float* fc_w   = (const float*)d_in[2];
    const float* fc_b   = (const float*)d_in[3];
    float* out = (float*)d_out;

    qnn_mfma<<<QNN_BATCH / (256 * QNN_TILES), 256, 0, stream>>>(x, params, fc_w, fc_b, out);
}

// Round 14
// 18.232 us; speedup vs baseline: 2.3492x; 1.0174x over previous
//
#include <hip/hip_runtime.h>
#include <math.h>

// QNN forward via MFMA:
//   psi_cat = M @ x  with M = [Re(U_kron); Im(U_kron)]  (32x16, bf16 A-frag)
//   one v_mfma_f32_32x32x16_bf16 per 32 samples; CNOT perm folded into wv;
//   norm via unitarity (n2 = sum_j |psi_j|^2).
// Wave-tile = 64 samples = 2 MFMAs. Block = 4 waves, QNN_TILES tiles/block.
//
// NOTE: QNN_TILES must stay 4. TILES=8 failed correctness twice (absmax
// ~0.23, R12/R13) with byte-identical per-sample math — unroll-depth-
// dependent codegen issue, mechanism not identified from source. 4 is the
// verified config (R11: absmax 0.0098, 18.55 us).
//
// Fragment layouts (guide-verified for 32x32x16 bf16):
//   A[row][k]: lane = row + 32*(k>>3), elem i = k&7   (8 bf16/lane)
//   B[k][n]:   lane = n  + 32*(k>>3), elem i = k&7   -> 8 consecutive floats
//              of sample n: two dwordx4 + 4 cvt_pk
//   D[row][col]: col = lane&31, row = (reg&3)+8*(reg>>2)+4*(lane>>5)
//     => lane holds yr_j (reg i) and yi_j (reg i+8) for j = (i&3)+8*(i>>2)+4h

#define QNN_BATCH 1048576
#define QNN_TILES 4

typedef float f32x16 __attribute__((ext_vector_type(16)));
typedef short bf16x8 __attribute__((ext_vector_type(8)));
typedef unsigned u32x4 __attribute__((ext_vector_type(4)));
typedef float vf4 __attribute__((ext_vector_type(4)));

__device__ __forceinline__ unsigned qnn_cvtpk(float lo, float hi) {
    unsigned r;
    asm("v_cvt_pk_bf16_f32 %0, %1, %2" : "=v"(r) : "v"(lo), "v"(hi));
    return r;
}

__device__ __forceinline__ int qnn_cnot_perm(int k, int c, int t) {
    int cbit = 1 << (3 - c), tbit = 1 << (3 - t);
    return (k & cbit) ? (k ^ tbit) : k;
}

__device__ __forceinline__ bf16x8 qnn_bfrag(vf4 a, vf4 b) {
    u32x4 u;
    u.x = qnn_cvtpk(a.x, a.y);
    u.y = qnn_cvtpk(a.z, a.w);
    u.z = qnn_cvtpk(b.x, b.y);
    u.w = qnn_cvtpk(b.z, b.w);
    return __builtin_bit_cast(bf16x8, u);
}

__global__ __launch_bounds__(256) void qnn_mfma(const float* __restrict__ x,
                                                const float* __restrict__ params,
                                                const float* __restrict__ fc_w,
                                                const float* __restrict__ fc_b,
                                                float* __restrict__ out) {
    __shared__ float g4[4][8];                 // per-qubit gates
    __shared__ float u01r[16], u01i[16];       // U0 (x) U1  (4x4 complex)
    __shared__ float u23r[16], u23i[16];       // U2 (x) U3
    __shared__ __align__(16) unsigned short afrag_lds[512];  // M bf16 A-frag
    __shared__ float wv_lds[48];               // wv[3][16], CNOT-permuted
    __shared__ float bias_lds[3];

    const int tid  = threadIdx.x;
    const int lane = tid & 63;
    const int wv_w = tid >> 6;          // wave id 0..3
    const int h    = lane >> 5;         // lane half (k-half / j-half)
    const int col  = lane & 31;         // sample column within mfma

    // ---- Issue tile-0 loads first (hide setup under them). ----
    const size_t blk0 = (size_t)blockIdx.x * (256 * QNN_TILES);
    const size_t wb0  = blk0 + wv_w * 64;          // tile 0, this wave
    const float* pa0 = x + (wb0 + col) * 16 + h * 8;
    const float* pb0 = x + (wb0 + 32 + col) * 16 + h * 8;
    vf4 cA0 = *(const vf4*)pa0, cA1 = *(const vf4*)(pa0 + 4);
    vf4 cB0 = *(const vf4*)pb0, cB1 = *(const vf4*)(pb0 + 4);

    // ---- Setup phase 1: gates (threads 0-3, one qubit each). ----
    if (tid < 4) {
        const int q = tid;
        float hx = 0.5f * params[q * 3 + 0];
        float hy = 0.5f * params[q * 3 + 1];
        float hz = 0.5f * params[q * 3 + 2];
        float cx = __cosf(hx), sx = __sinf(hx);
        float cy = __cosf(hy), sy = __sinf(hy);
        float cz = __cosf(hz), sz = __sinf(hz);
        float A = cy * cx, B = sy * sx, C = sy * cx, D = cy * sx;
        g4[q][0] =  cz * A + sz * B;   // g00 re
        g4[q][1] =  cz * B - sz * A;   // g00 im
        g4[q][2] = -cz * C - sz * D;   // g01 re
        g4[q][3] =  sz * C - cz * D;   // g01 im
        g4[q][4] =  cz * C + sz * D;   // g10 re
        g4[q][5] =  sz * C - cz * D;   // g10 im
        g4[q][6] =  cz * A + sz * B;   // g11 re
        g4[q][7] =  sz * A - cz * B;   // g11 im
    }
    __syncthreads();

    // ---- Setup phase 2: 4x4 krons, wv, bias (parallel). ----
    if (tid < 32) {
        const int e = tid & 15, a = e >> 2, b = e & 3;
        const int q0 = (tid < 16) ? 0 : 2, q1 = q0 + 1;
        const float xr = g4[q0][4 * (a >> 1) + 2 * (b >> 1)];
        const float xi = g4[q0][4 * (a >> 1) + 2 * (b >> 1) + 1];
        const float yr = g4[q1][4 * (a & 1) + 2 * (b & 1)];
        const float yi = g4[q1][4 * (a & 1) + 2 * (b & 1) + 1];
        if (tid < 16) { u01r[e] = xr * yr - xi * yi; u01i[e] = xr * yi + xi * yr; }
        else          { u23r[e] = xr * yr - xi * yi; u23i[e] = xr * yi + xi * yr; }
    } else if (tid >= 64 && tid < 112) {
        const int idx = tid - 64, c = idx >> 4, o = idx & 15;
        const int j = qnn_cnot_perm(qnn_cnot_perm(qnn_cnot_perm(o, 2, 3), 1, 2), 0, 1);
        float s = 0.f;
        for (int ww = 0; ww < 4; ++ww) {
            float z = 1.f - 2.f * (float)((o >> (3 - ww)) & 1);
            s += fc_w[c * 4 + ww] * z;
        }
        wv_lds[c * 16 + j] = s;
    } else if (tid >= 112 && tid < 115) {
        bias_lds[tid - 112] = fc_b[tid - 112];
    }
    __syncthreads();

    // ---- Setup phase 3: M entry (j,k) per thread -> bf16 A-fragment. ----
    {
        const int j = tid >> 4, k = tid & 15;
        const float ar = u01r[(j >> 2) * 4 + (k >> 2)];
        const float ai = u01i[(j >> 2) * 4 + (k >> 2)];
        const float br = u23r[(j & 3) * 4 + (k & 3)];
        const float bi = u23i[(j & 3) * 4 + (k & 3)];
        const float re = ar * br - ai * bi;   // M[j][k]   (row j    = Re)
        const float im = ar * bi + ai * br;   // M[j+16][k] (row j+16 = Im)
        const unsigned pk = qnn_cvtpk(re, im);
        const int laneR = j + ((k >> 3) << 5);
        const int laneI = (j + 16) + ((k >> 3) << 5);
        afrag_lds[laneR * 8 + (k & 7)] = (unsigned short)(pk & 0xffffu);
        afrag_lds[laneI * 8 + (k & 7)] = (unsigned short)(pk >> 16);
    }
    __syncthreads();

    // ---- Per-lane persistent fragments. ----
    const bf16x8 afrag = *(const bf16x8*)&afrag_lds[lane * 8];
    float wv0[8], wv1[8], wv2[8];
#pragma unroll
    for (int i = 0; i < 8; ++i) {
        const int j = (i & 3) + 8 * (i >> 2) + 4 * h;
        wv0[i] = wv_lds[j];
        wv1[i] = wv_lds[16 + j];
        wv2[i] = wv_lds[32 + j];
    }
    const float bs0 = bias_lds[0], bs1 = bias_lds[1], bs2 = bias_lds[2];

    // ---- Tile loop with distance-1 prefetch. ----
#pragma unroll
    for (int k = 0; k < QNN_TILES; ++k) {
        vf4 nA0, nA1, nB0, nB1;
        if (k + 1 < QNN_TILES) {
            const size_t wbn = blk0 + (size_t)(k + 1) * 256 + wv_w * 64;
            const float* pa = x + (wbn + col) * 16 + h * 8;
            const float* pb = x + (wbn + 32 + col) * 16 + h * 8;
            nA0 = *(const vf4*)pa; nA1 = *(const vf4*)(pa + 4);
            nB0 = *(const vf4*)pb; nB1 = *(const vf4*)(pb + 4);
        }

        const bf16x8 fb0 = qnn_bfrag(cA0, cA1);
        const bf16x8 fb1 = qnn_bfrag(cB0, cB1);
        f32x16 zacc = {0.f,0.f,0.f,0.f,0.f,0.f,0.f,0.f,
                       0.f,0.f,0.f,0.f,0.f,0.f,0.f,0.f};
        const f32x16 d0 = __builtin_amdgcn_mfma_f32_32x32x16_bf16(afrag, fb0, zacc, 0, 0, 0);
        const f32x16 d1 = __builtin_amdgcn_mfma_f32_32x32x16_bf16(afrag, fb1, zacc, 0, 0, 0);

        // probs + partial contraction for each mfma (lane-local 8 j's).
        float pA[8], pB[8];
#pragma unroll
        for (int i = 0; i < 8; ++i) {
            pA[i] = fmaf(d0[i], d0[i], d0[i + 8] * d0[i + 8]);
            pB[i] = fmaf(d1[i], d1[i], d1[i + 8] * d1[i + 8]);
        }
        float LA0 = 0.f, LA1 = 0.f, LA2 = 0.f;
        float LB0 = 0.f, LB1 = 0.f, LB2 = 0.f;
#pragma unroll
        for (int i = 0; i < 8; ++i) {
            LA0 = fmaf(wv0[i], pA[i], LA0);
            LA1 = fmaf(wv1[i], pA[i], LA1);
            LA2 = fmaf(wv2[i], pA[i], LA2);
            LB0 = fmaf(wv0[i], pB[i], LB0);
            LB1 = fmaf(wv1[i], pB[i], LB1);
            LB2 = fmaf(wv2[i], pB[i], LB2);
        }
        const float NSA = ((pA[0] + pA[1]) + (pA[2] + pA[3])) +
                          ((pA[4] + pA[5]) + (pA[6] + pA[7]));
        const float NSB = ((pB[0] + pB[1]) + (pB[2] + pB[3])) +
                          ((pB[4] + pB[5]) + (pB[6] + pB[7]));

        // Exchange: lane keeps mfma_h (h=0 -> mfma0); sends the other's
        // partials to its pair lane (l ^ 32), which is the lane that keeps it.
        const float s0 = h ? LA0 : LB0, s1 = h ? LA1 : LB1;
        const float s2 = h ? LA2 : LB2, s3 = h ? NSA : NSB;
        const float r0 = __shfl_xor(s0, 32, 64);
        const float r1 = __shfl_xor(s1, 32, 64);
        const float r2 = __shfl_xor(s2, 32, 64);
        const float r3 = __shfl_xor(s3, 32, 64);
        const float L0 = (h ? LB0 : LA0) + r0;
        const float L1 = (h ? LB1 : LA1) + r1;
        const float L2 = (h ? LB2 : LA2) + r2;
        const float NS = (h ? NSB : NSA) + r3;

        const float inv = __builtin_amdgcn_rcpf(NS);
        const size_t wb = blk0 + (size_t)k * 256 + wv_w * 64;
        float* o = out + (wb + lane) * 3;
        o[0] = fmaf(L0, inv, bs0);
        o[1] = fmaf(L1, inv, bs1);
        o[2] = fmaf(L2, inv, bs2);

        if (k + 1 < QNN_TILES) { cA0 = nA0; cA1 = nA1; cB0 = nB0; cB1 = nB1; }
    }
}

extern "C" void kernel_launch(void* const* d_in, const int* in_sizes, int n_in,
                              void* d_out, int out_size, void* d_ws, size_t ws_size,
                              hipStream_t stream) {
    (void)in_sizes; (void)n_in; (void)out_size; (void)d_ws; (void)ws_size;
    const float* x      = (const float*)d_in[0];
    const float* params = (const float*)d_in[1];
    const float* fc_w   = (const float*)d_in[2];
    const float* fc_b   = (const float*)d_in[3];
    float* out = (float*)d_out;

    qnn_mfma<<<QNN_BATCH / (256 * QNN_TILES), 256, 0, stream>>>(x, params, fc_w, fc_b, out);
}